// Round 6
// baseline (368.693 us; speedup 1.0000x reference)
//
#include <hip/hip_runtime.h>
#include <stdint.h>

// GraphSAGE 2-layer, MI355X. Round 6: bucket-partitioned CSR build.
//   k_part: edges -> 8 dst-range buckets, packed u32 (src<<14|dlocal),
//           LDS-staged coalesced flushes (reads+writes all coalesced).
//   k_degree_s / k_scatter_s: per-slice (XCD-local) passes whose ENTIRE
//           working set (0.8MB packed stream + deg/cursor + srclist region)
//           fits one XCD's 4MB L2 -> random 4B writes merge into full lines.
//   k_scan_slice: per-slice scan (bucket counts give each slice's edge base).
// Then: z1|r1 = x@[W1l|W1r] (MFMA), h = relu(mean_agg(z1)+r1+b1),
//       z2|r2 = h@[W2l|W2r] (MFMA, z2 padded to 64ch),
//       out = log_softmax(mean_agg(z2)+r2+b2).

typedef unsigned int uint32;
typedef unsigned short u16;
typedef __bf16 bf16x8 __attribute__((ext_vector_type(8)));
typedef float  f32x4  __attribute__((ext_vector_type(4)));
typedef unsigned short u16x8 __attribute__((ext_vector_type(8)));

__device__ __forceinline__ float bf2f(u16 u) {
    union { uint32 i; float f; } v; v.i = ((uint32)u) << 16; return v.f;
}
__device__ __forceinline__ u16 f2bf(float f) {
    union { float f; uint32 i; } v; v.f = f;
    uint32 i = v.i;
    uint32 r = (i + 0x7FFFu + ((i >> 16) & 1u)) >> 16;  // RNE
    return (u16)r;
}
__device__ __forceinline__ bf16x8 cvt8(float4 a, float4 b) {
    bf16x8 r;
    r[0] = (__bf16)a.x; r[1] = (__bf16)a.y; r[2] = (__bf16)a.z; r[3] = (__bf16)a.w;
    r[4] = (__bf16)b.x; r[5] = (__bf16)b.y; r[6] = (__bf16)b.z; r[7] = (__bf16)b.w;
    return r;
}

// ---------------- bucket partition: edges -> part[8 buckets], packed ----------
// Tile = 1024 edges/block-iter. LDS buffers per bucket, coalesced flush with
// one global atomic per non-empty bucket per tile.
__global__ __launch_bounds__(256) void k_part(const int* __restrict__ src,
        const int* __restrict__ dst, uint32* __restrict__ part,
        int* __restrict__ gcur, int E, int sw, uint32 magic, int cap) {
    __shared__ uint32 buf[8][1024];
    __shared__ int lcnt[8], gbase[8];
    int ntiles = (E + 1023) >> 10;
    for (int tile = blockIdx.x; tile < ntiles; tile += gridDim.x) {
        if (threadIdx.x < 8) lcnt[threadIdx.x] = 0;
        __syncthreads();
        int e0 = (tile << 10) + threadIdx.x * 4;
        if (e0 + 3 < E) {
            int4 d4 = *(const int4*)(dst + e0);
            int4 s4 = *(const int4*)(src + e0);
            int dd[4] = {d4.x, d4.y, d4.z, d4.w};
            int ss[4] = {s4.x, s4.y, s4.z, s4.w};
#pragma unroll
            for (int k = 0; k < 4; ++k) {
                int b = (int)(((unsigned long long)(uint32)dd[k] * magic) >> 32);
                uint32 pk = ((uint32)ss[k] << 14) | (uint32)(dd[k] - b * sw);
                int slot = atomicAdd(&lcnt[b], 1);
                buf[b][slot] = pk;
            }
        } else {
            for (int e = e0; e < E && e < e0 + 4; ++e) {
                int d = dst[e];
                int b = (int)(((unsigned long long)(uint32)d * magic) >> 32);
                uint32 pk = ((uint32)src[e] << 14) | (uint32)(d - b * sw);
                int slot = atomicAdd(&lcnt[b], 1);
                buf[b][slot] = pk;
            }
        }
        __syncthreads();
        if (threadIdx.x < 8 && lcnt[threadIdx.x] > 0)
            gbase[threadIdx.x] = atomicAdd(&gcur[threadIdx.x], lcnt[threadIdx.x]);
        __syncthreads();
#pragma unroll
        for (int b = 0; b < 8; ++b) {
            int n = lcnt[b];
            if (n == 0) continue;
            int gb = gbase[b];
            int lim = (b + 1) * cap;   // safety clamp (never hit for our sizes)
            for (int i = threadIdx.x; i < n; i += 256) {
                int p = gb + i;
                if (p < lim) part[p] = buf[b][i];
            }
        }
        __syncthreads();
    }
}

// ---------------- sliced degree histogram over packed buckets ----------------
__global__ __launch_bounds__(256) void k_degree_s(const uint32* __restrict__ part,
        const int* __restrict__ gcur, int* __restrict__ deg, int sw, int cap) {
    int s = blockIdx.x & 7, g = blockIdx.x >> 3;
    int m = gcur[s] - s * cap;
    const uint32* p = part + (size_t)s * cap;
    int base = s * sw;
    int t = g * 256 + threadIdx.x;
    int stride = (gridDim.x >> 3) * 256;
    int m4 = m >> 2;
    for (int i = t; i < m4; i += stride) {
        uint4 v = ((const uint4*)p)[i];
        atomicAdd(&deg[base + (v.x & 16383)], 1);
        atomicAdd(&deg[base + (v.y & 16383)], 1);
        atomicAdd(&deg[base + (v.z & 16383)], 1);
        atomicAdd(&deg[base + (v.w & 16383)], 1);
    }
    for (int i = (m4 << 2) + t; i < m; i += stride)
        atomicAdd(&deg[base + (p[i] & 16383)], 1);
}

// ---------------- per-slice scan: deg -> rowstart/cursor ----------------
// Block s scans its slice; edge base = sum of bucket counts before s.
__global__ __launch_bounds__(1024) void k_scan_slice(const int* __restrict__ deg,
        const int* __restrict__ gcur, int* __restrict__ rowstart,
        int* __restrict__ cursor, int N, int sw, int cap) {
    __shared__ int sums[1024];
    int s = blockIdx.x;
    int base = 0;
    for (int b = 0; b < s; ++b) base += gcur[b] - b * cap;
    int lo = s * sw;
    int cnt = min(sw, N - lo);
    if (cnt <= 0) return;
    int ch = (cnt + 1023) >> 10;
    int t = threadIdx.x;
    int a0 = min(t * ch, cnt), a1 = min(a0 + ch, cnt);
    int loc = 0;
    for (int i = a0; i < a1; ++i) loc += deg[lo + i];
    sums[t] = loc;
    __syncthreads();
    for (int off = 1; off < 1024; off <<= 1) {
        int u = (t >= off) ? sums[t - off] : 0;
        __syncthreads();
        sums[t] += u;
        __syncthreads();
    }
    int excl = base + sums[t] - loc;
    for (int i = a0; i < a1; ++i) {
        rowstart[lo + i] = excl;
        cursor[lo + i] = excl;
        excl += deg[lo + i];
    }
    if (lo + cnt == N && t == 1023) rowstart[N] = base + sums[1023];
}

// ---------------- sliced scatter over packed buckets ----------------
__global__ __launch_bounds__(256) void k_scatter_s(const uint32* __restrict__ part,
        const int* __restrict__ gcur, int* __restrict__ cursor,
        int* __restrict__ srclist, int sw, int cap) {
    int s = blockIdx.x & 7, g = blockIdx.x >> 3;
    int m = gcur[s] - s * cap;
    const uint32* p = part + (size_t)s * cap;
    int base = s * sw;
    int t = g * 256 + threadIdx.x;
    int stride = (gridDim.x >> 3) * 256;
    int m4 = m >> 2;
    for (int i = t; i < m4; i += stride) {
        uint4 v = ((const uint4*)p)[i];
        srclist[atomicAdd(&cursor[base + (v.x & 16383)], 1)] = (int)(v.x >> 14);
        srclist[atomicAdd(&cursor[base + (v.y & 16383)], 1)] = (int)(v.y >> 14);
        srclist[atomicAdd(&cursor[base + (v.z & 16383)], 1)] = (int)(v.z >> 14);
        srclist[atomicAdd(&cursor[base + (v.w & 16383)], 1)] = (int)(v.w >> 14);
    }
    for (int i = (m4 << 2) + t; i < m; i += stride) {
        uint32 v = p[i];
        srclist[atomicAdd(&cursor[base + (v & 16383)], 1)] = (int)(v >> 14);
    }
}

// ---------------- weight prep: transpose + bf16 (+ gcur init) ----------------
__global__ void k_prep(const float* __restrict__ W1l, const float* __restrict__ W1r,
                       const float* __restrict__ W2l, const float* __restrict__ W2r,
                       u16* __restrict__ Wt1, u16* __restrict__ Wt2,
                       int* __restrict__ gcur, int cap) {
    if (blockIdx.x == 0 && threadIdx.x < 8) gcur[threadIdx.x] = threadIdx.x * cap;
    if (blockIdx.x < 128) {
        int idx = blockIdx.x * 256 + threadIdx.x;
        int c = idx >> 7, k = idx & 127;
        float v = (c < 128) ? W1l[k * 128 + c] : W1r[k * 128 + (c - 128)];
        Wt1[idx] = f2bf(v);
    } else {
        int idx = (blockIdx.x - 128) * 256 + threadIdx.x;  // 96*128 total
        int c = idx >> 7, k = idx & 127;
        const float* W = (c < 48) ? W2l : W2r;
        int cc = (c < 48) ? c : c - 48;
        float v = (cc < 40) ? W[k * 40 + cc] : 0.f;
        Wt2[idx] = f2bf(v);
    }
}

// ---------------- Layer-1 GEMM (MFMA): [n,128]f32 x [128,256]bf16 -> z1|r1 ----
__global__ __launch_bounds__(512) void k_gemm1(const float* __restrict__ x,
        const u16* __restrict__ Wt,
        u16* __restrict__ z1, u16* __restrict__ r1, int N) {
    int lane = threadIdx.x & 63;
    int w    = threadIdx.x >> 6;
    int l15 = lane & 15, g = lane >> 4;
    int rbase = blockIdx.x * 128 + (w >> 2) * 64;
    int cbase = (w & 3) * 64;

    bf16x8 Bf[4][4];
#pragma unroll
    for (int c = 0; c < 4; ++c)
#pragma unroll
        for (int ks = 0; ks < 4; ++ks)
            Bf[c][ks] = *(const bf16x8*)(Wt + (((size_t)(cbase + c * 16 + l15)) << 7)
                                            + ks * 32 + g * 8);

    f32x4 acc[4][4];
    f32x4 z4 = {0.f, 0.f, 0.f, 0.f};
#pragma unroll
    for (int r = 0; r < 4; ++r)
#pragma unroll
        for (int c = 0; c < 4; ++c) acc[r][c] = z4;

#pragma unroll
    for (int ks = 0; ks < 4; ++ks) {
        bf16x8 Af[4];
#pragma unroll
        for (int r = 0; r < 4; ++r) {
            int row = rbase + r * 16 + l15;
            row = row < N ? row : N - 1;          // clamp: no OOB read
            const float* ap = x + (((size_t)row) << 7) + ks * 32 + g * 8;
            float4 lo = *(const float4*)ap;
            float4 hi = *(const float4*)(ap + 4);
            Af[r] = cvt8(lo, hi);
        }
#pragma unroll
        for (int r = 0; r < 4; ++r)
#pragma unroll
            for (int c = 0; c < 4; ++c)
                acc[r][c] = __builtin_amdgcn_mfma_f32_16x16x32_bf16(
                                Af[r], Bf[c][ks], acc[r][c], 0, 0, 0);
    }

    // C/D layout: col = lane&15, row = (lane>>4)*4 + j
#pragma unroll
    for (int r = 0; r < 4; ++r) {
#pragma unroll
        for (int c = 0; c < 4; ++c) {
            int col = cbase + c * 16 + l15;
            u16* out = (col < 128) ? z1 : r1;
            int cc = col & 127;
#pragma unroll
            for (int j = 0; j < 4; ++j) {
                int row = rbase + r * 16 + g * 4 + j;
                if (row < N) out[((size_t)row << 7) + cc] = f2bf(acc[r][c][j]);
            }
        }
    }
}

// ---------------- Layer-2 GEMM (MFMA): [n,128]bf16 x [128,96]bf16 ----
__global__ __launch_bounds__(512) void k_gemm2(const u16* __restrict__ hb,
        const u16* __restrict__ Wt2,
        u16* __restrict__ z2p, u16* __restrict__ r2, int N) {
    int lane = threadIdx.x & 63;
    int w    = threadIdx.x >> 6;
    int l15 = lane & 15, g = lane >> 4;
    int rbase = blockIdx.x * 256 + (w >> 1) * 64;
    int half  = w & 1;

    bf16x8 Bf[3][4];
#pragma unroll
    for (int c = 0; c < 3; ++c)
#pragma unroll
        for (int ks = 0; ks < 4; ++ks)
            Bf[c][ks] = *(const bf16x8*)(Wt2 + (((size_t)(half * 48 + c * 16 + l15)) << 7)
                                             + ks * 32 + g * 8);

    f32x4 acc[4][3];
    f32x4 z4 = {0.f, 0.f, 0.f, 0.f};
#pragma unroll
    for (int r = 0; r < 4; ++r)
#pragma unroll
        for (int c = 0; c < 3; ++c) acc[r][c] = z4;

#pragma unroll
    for (int ks = 0; ks < 4; ++ks) {
        bf16x8 Af[4];
#pragma unroll
        for (int r = 0; r < 4; ++r) {
            int row = rbase + r * 16 + l15;
            row = row < N ? row : N - 1;
            Af[r] = *(const bf16x8*)(hb + (((size_t)row) << 7) + ks * 32 + g * 8);
        }
#pragma unroll
        for (int r = 0; r < 4; ++r)
#pragma unroll
            for (int c = 0; c < 3; ++c)
                acc[r][c] = __builtin_amdgcn_mfma_f32_16x16x32_bf16(
                                Af[r], Bf[c][ks], acc[r][c], 0, 0, 0);
    }

    if (half == 0) {
#pragma unroll
        for (int r = 0; r < 4; ++r)
#pragma unroll
            for (int c = 0; c < 3; ++c) {
                int col = c * 16 + l15;
#pragma unroll
                for (int j = 0; j < 4; ++j) {
                    int row = rbase + r * 16 + g * 4 + j;
                    if (row < N) z2p[((size_t)row << 6) + col] = f2bf(acc[r][c][j]);
                }
            }
        int row = rbase + lane;   // zero-fill cols 48..63 of 64 rows
        if (row < N) {
            u16x8 z8 = {0, 0, 0, 0, 0, 0, 0, 0};
            *(u16x8*)(z2p + ((size_t)row << 6) + 48) = z8;
            *(u16x8*)(z2p + ((size_t)row << 6) + 56) = z8;
        }
    } else {
#pragma unroll
        for (int r = 0; r < 4; ++r)
#pragma unroll
            for (int c = 0; c < 3; ++c) {
                int col = c * 16 + l15;
                if (col < 40) {
#pragma unroll
                    for (int j = 0; j < 4; ++j) {
                        int row = rbase + r * 16 + g * 4 + j;
                        if (row < N) r2[(size_t)row * 40 + col] = f2bf(acc[r][c][j]);
                    }
                }
            }
    }
}

// ---------------- Layer-1 aggregation ----------------
// Wave per node. 4 edges per gather: g=lane>>4 -> edge, c=lane&15 -> 16B slice.
__global__ __launch_bounds__(256) void k_agg1(const u16* __restrict__ z1,
        const u16* __restrict__ r1, const float* __restrict__ b1,
        const int* __restrict__ rowstart, const int* __restrict__ srclist,
        u16* __restrict__ h, int n) {
    int wid = (blockIdx.x * 256 + threadIdx.x) >> 6;
    int lane = threadIdx.x & 63;
    if (wid >= n) return;
    int g = lane >> 4, c = lane & 15;
    int s0 = rowstart[wid], s1 = rowstart[wid + 1];
    float acc[8];
#pragma unroll
    for (int i = 0; i < 8; ++i) acc[i] = 0.f;

    int j = s0 + g;
    for (; j + 12 < s1; j += 16) {
        int sA = srclist[j], sB = srclist[j + 4];
        int sC = srclist[j + 8], sD = srclist[j + 12];
        u16x8 a = *(const u16x8*)(z1 + ((size_t)sA << 7) + c * 8);
        u16x8 b = *(const u16x8*)(z1 + ((size_t)sB << 7) + c * 8);
        u16x8 d = *(const u16x8*)(z1 + ((size_t)sC << 7) + c * 8);
        u16x8 e = *(const u16x8*)(z1 + ((size_t)sD << 7) + c * 8);
#pragma unroll
        for (int i = 0; i < 8; ++i)
            acc[i] += (bf2f(a[i]) + bf2f(b[i])) + (bf2f(d[i]) + bf2f(e[i]));
    }
    for (; j + 4 < s1; j += 8) {
        int sA = srclist[j], sB = srclist[j + 4];
        u16x8 a = *(const u16x8*)(z1 + ((size_t)sA << 7) + c * 8);
        u16x8 b = *(const u16x8*)(z1 + ((size_t)sB << 7) + c * 8);
#pragma unroll
        for (int i = 0; i < 8; ++i) acc[i] += bf2f(a[i]) + bf2f(b[i]);
    }
    if (j < s1) {
        int sA = srclist[j];
        u16x8 a = *(const u16x8*)(z1 + ((size_t)sA << 7) + c * 8);
#pragma unroll
        for (int i = 0; i < 8; ++i) acc[i] += bf2f(a[i]);
    }
#pragma unroll
    for (int i = 0; i < 8; ++i) {
        acc[i] += __shfl_xor(acc[i], 16, 64);
        acc[i] += __shfl_xor(acc[i], 32, 64);
    }
    if (g == 0) {
        float inv = 1.0f / fmaxf((float)(s1 - s0), 1.0f);
        u16x8 rv = *(const u16x8*)(r1 + ((size_t)wid << 7) + c * 8);
        float4 b0 = *(const float4*)(b1 + c * 8);
        float4 b4 = *(const float4*)(b1 + c * 8 + 4);
        float bb[8] = {b0.x, b0.y, b0.z, b0.w, b4.x, b4.y, b4.z, b4.w};
        u16x8 o;
#pragma unroll
        for (int i = 0; i < 8; ++i)
            o[i] = f2bf(fmaxf(acc[i] * inv + bf2f(rv[i]) + bb[i], 0.f));
        *(u16x8*)(h + ((size_t)wid << 7) + c * 8) = o;
    }
}

// ---------------- Layer-2 aggregation + log_softmax ----------------
__global__ __launch_bounds__(256) void k_agg2(const u16* __restrict__ z2p,
        const u16* __restrict__ r2, const float* __restrict__ b2,
        const int* __restrict__ rowstart, const int* __restrict__ srclist,
        float* __restrict__ out, int n) {
    int wid = (blockIdx.x * 256 + threadIdx.x) >> 6;
    int lane = threadIdx.x & 63;
    if (wid >= n) return;
    int le = lane >> 3, c = lane & 7;
    int s0 = rowstart[wid], s1 = rowstart[wid + 1];
    float acc[8];
#pragma unroll
    for (int i = 0; i < 8; ++i) acc[i] = 0.f;

    int j = s0 + le;
    for (; j + 8 < s1; j += 16) {
        int sA = srclist[j], sB = srclist[j + 8];
        u16x8 a = *(const u16x8*)(z2p + ((size_t)sA << 6) + c * 8);
        u16x8 b = *(const u16x8*)(z2p + ((size_t)sB << 6) + c * 8);
#pragma unroll
        for (int i = 0; i < 8; ++i) acc[i] += bf2f(a[i]) + bf2f(b[i]);
    }
    if (j < s1) {
        int sA = srclist[j];
        u16x8 a = *(const u16x8*)(z2p + ((size_t)sA << 6) + c * 8);
#pragma unroll
        for (int i = 0; i < 8; ++i) acc[i] += bf2f(a[i]);
    }
#pragma unroll
    for (int i = 0; i < 8; ++i) {
        acc[i] += __shfl_xor(acc[i], 8, 64);
        acc[i] += __shfl_xor(acc[i], 16, 64);
        acc[i] += __shfl_xor(acc[i], 32, 64);
    }
    if (le == 0) {   // lanes 0..7: channels c*8..c*8+7; only c<5 real (40 ch)
        float inv = 1.0f / fmaxf((float)(s1 - s0), 1.0f);
        bool act = c < 5;
        float v[8];
        if (act) {
            u16x8 rv = *(const u16x8*)(r2 + (size_t)wid * 40 + c * 8);
            float4 b0 = *(const float4*)(b2 + c * 8);
            float4 b4 = *(const float4*)(b2 + c * 8 + 4);
            float bb[8] = {b0.x, b0.y, b0.z, b0.w, b4.x, b4.y, b4.z, b4.w};
#pragma unroll
            for (int i = 0; i < 8; ++i) v[i] = acc[i] * inv + bf2f(rv[i]) + bb[i];
        } else {
#pragma unroll
            for (int i = 0; i < 8; ++i) v[i] = -1e30f;
        }
        float m = v[0];
#pragma unroll
        for (int i = 1; i < 8; ++i) m = fmaxf(m, v[i]);
        m = fmaxf(m, __shfl_xor(m, 1, 64));
        m = fmaxf(m, __shfl_xor(m, 2, 64));
        m = fmaxf(m, __shfl_xor(m, 4, 64));
        float s = 0.f;
        if (act) {
#pragma unroll
            for (int i = 0; i < 8; ++i) s += __expf(v[i] - m);
        }
        s += __shfl_xor(s, 1, 64);
        s += __shfl_xor(s, 2, 64);
        s += __shfl_xor(s, 4, 64);
        float lse = __logf(s);
        if (act) {
            float4 o0, o4;
            o0.x = v[0] - m - lse; o0.y = v[1] - m - lse;
            o0.z = v[2] - m - lse; o0.w = v[3] - m - lse;
            o4.x = v[4] - m - lse; o4.y = v[5] - m - lse;
            o4.z = v[6] - m - lse; o4.w = v[7] - m - lse;
            *(float4*)(out + (size_t)wid * 40 + c * 8) = o0;
            *(float4*)(out + (size_t)wid * 40 + c * 8 + 4) = o4;
        }
    }
}

extern "C" void kernel_launch(void* const* d_in, const int* in_sizes, int n_in,
                              void* d_out, int out_size, void* d_ws, size_t ws_size,
                              hipStream_t stream) {
    const float* x   = (const float*)d_in[0];
    const int*   ei  = (const int*)d_in[1];   // [2][E] int32
    const float* W1l = (const float*)d_in[2];
    const float* W1r = (const float*)d_in[3];
    const float* b1  = (const float*)d_in[4];
    const float* W2l = (const float*)d_in[5];
    const float* W2r = (const float*)d_in[6];
    const float* b2  = (const float*)d_in[7];
    float* out = (float*)d_out;

    int N = in_sizes[0] / 128;
    int E = in_sizes[1] / 2;
    const int* esrc = ei;
    const int* edst = ei + E;

    int sw = (N + 7) / 8;                                  // 12500
    uint32 magic = (uint32)((((unsigned long long)1 << 32) + sw - 1) / sw);
    int cap = (((E >> 3) + 8192) + 3) & ~3;                // per-bucket capacity

    // workspace carve (256B aligned)
    char* p = (char*)d_ws;
    size_t off = 0;
    auto alloc = [&](size_t bytes) {
        void* q = p + off;
        off = (off + bytes + 255) & ~(size_t)255;
        return q;
    };
    int* deg      = (int*)alloc((size_t)N * 4);
    int* rowstart = (int*)alloc((size_t)(N + 1) * 4);
    int* cursor   = (int*)alloc((size_t)N * 4);
    int* gcur     = (int*)alloc(64);
    u16* Wt1 = (u16*)alloc(256 * 128 * 2);
    u16* Wt2 = (u16*)alloc(96 * 128 * 2);
    int* srclist  = (int*)alloc((size_t)E * 4);
    uint32* part  = (uint32*)alloc((size_t)8 * cap * 4);
    u16* z1 = (u16*)alloc((size_t)N * 128 * 2);
    u16* r1 = (u16*)alloc((size_t)N * 128 * 2);
    u16* hb = r1;                         // h aliases r1 (elementwise)
    u16* z2p = z1;                        // reuse z1 (dead after k_agg1)
    u16* r2  = z1 + (size_t)N * 64;

    hipMemsetAsync(deg, 0, (size_t)N * 4, stream);
    k_prep<<<176, 256, 0, stream>>>(W1l, W1r, W2l, W2r, Wt1, Wt2, gcur, cap);
    k_part<<<1024, 256, 0, stream>>>(esrc, edst, part, gcur, E, sw, magic, cap);
    k_degree_s<<<2048, 256, 0, stream>>>(part, gcur, deg, sw, cap);
    k_scan_slice<<<8, 1024, 0, stream>>>(deg, gcur, rowstart, cursor, N, sw, cap);
    k_scatter_s<<<2048, 256, 0, stream>>>(part, gcur, cursor, srclist, sw, cap);

    k_gemm1<<<(N + 127) / 128, 512, 0, stream>>>(x, Wt1, z1, r1, N);
    k_agg1<<<(N + 3) / 4, 256, 0, stream>>>(z1, r1, b1, rowstart, srclist, hb, N);
    k_gemm2<<<(N + 255) / 256, 512, 0, stream>>>(hb, Wt2, z2p, r2, N);
    k_agg2<<<(N + 3) / 4, 256, 0, stream>>>(z2p, r2, b2, rowstart, srclist, out, N);
}